// Round 1
// baseline (80.807 us; speedup 1.0000x reference)
//
#include <hip/hip_runtime.h>
#include <stdint.h>
#include <stddef.h>

#define BATCH 256
#define IN_F  4096
#define OUT_F 4096
#define BN    16
#define BK    64
#define NT    (IN_F / BK)   // 64 k-steps
#define TPB   512           // 8 waves

typedef __attribute__((ext_vector_type(8))) short    bf16x8;
typedef __attribute__((ext_vector_type(4))) float    f32x4;
typedef __attribute__((ext_vector_type(2))) float    f32x2;
typedef __attribute__((ext_vector_type(4))) uint32_t u32x4;

#define MFMA(a, b, c) __builtin_amdgcn_mfma_f32_16x16x32_bf16((a), (b), (c), 0, 0, 0)

// fp32 -> bf16 round-to-nearest-even, two at a time packed into u32 (lo=a, hi=b)
__device__ __forceinline__ uint32_t pack2bf(float a, float b) {
  uint32_t ua = __builtin_bit_cast(uint32_t, a);
  uint32_t ub = __builtin_bit_cast(uint32_t, b);
  ua += 0x7FFFu + ((ua >> 16) & 1u);
  ub += 0x7FFFu + ((ub >> 16) & 1u);
  return (ua >> 16) | (ub & 0xFFFF0000u);
}

// 8 consecutive fp32 -> bf16x8 (RNE)
__device__ __forceinline__ bf16x8 cvt8(const float* __restrict__ p) {
  f32x4 v0 = *(const f32x4*)p;
  f32x4 v1 = *(const f32x4*)(p + 4);
  union { u32x4 u; bf16x8 h; } r;
  r.u[0] = pack2bf(v0[0], v0[1]);
  r.u[1] = pack2bf(v0[2], v0[3]);
  r.u[2] = pack2bf(v1[0], v1[1]);
  r.u[3] = pack2bf(v1[2], v1[3]);
  return r.h;
}

// ---------------------------------------------------------------------------
// Prep: x (fp32 [256][4096]) -> bf16 [256][4096] in ws; bias = bmu + beps*exp(.5*blv)
// blocks 0..511: x conversion (1x 16B-chunk/thread). blocks 512..527: bias.
// ---------------------------------------------------------------------------
__global__ __launch_bounds__(256) void prep_kernel(
    const float* __restrict__ x,
    const float* __restrict__ bmu,
    const float* __restrict__ blv,
    const float* __restrict__ beps,
    u32x4* __restrict__ xs4,
    float* __restrict__ bias)
{
  const uint32_t b = blockIdx.x;
  if (b < 512u) {
    const uint32_t c = b * 256u + threadIdx.x;       // chunk of 8 floats
    const float* p = x + (size_t)c * 8u;
    f32x4 v0 = *(const f32x4*)p;
    f32x4 v1 = *(const f32x4*)(p + 4);
    u32x4 o;
    o[0] = pack2bf(v0[0], v0[1]);
    o[1] = pack2bf(v0[2], v0[3]);
    o[2] = pack2bf(v1[0], v1[1]);
    o[3] = pack2bf(v1[2], v1[3]);
    xs4[c] = o;
  } else {
    const uint32_t i = (b - 512u) * 256u + threadIdx.x;  // 0..4095
    float s = exp2f(blv[i] * 0.7213475204444817f);       // exp(0.5*lv)
    bias[i] = fmaf(beps[i], s, bmu[i]);
  }
}

// ---------------------------------------------------------------------------
// Main fused GEMM: y[m][n] = sum_k x[m][k]*W[n][k] + bias[n],
//                  W[n][k] = mu + eps*exp(0.5*lv) computed on the fly.
// Grid: 256 WGs (one per CU), WG = 8 waves, BN=16 cols, BM=256 (full batch).
// W tile (16x64) double-buffered in LDS, XOR-swizzled (slot ^= row&7).
// a-frags (x) loaded global->reg (L2-resident), distance-1 prefetch.
// W raw fp32 loads distance-2 prefetch; raw s_barrier + lgkmcnt(0) only, so
// prefetched global loads stay in flight across the barrier.
// ---------------------------------------------------------------------------
template<bool USE_XS>
__global__ __launch_bounds__(TPB)
void vgemm_kernel(const uint16_t* __restrict__ xs,   // bf16 x (USE_XS)
                  const float*    __restrict__ xf,   // fp32 x (!USE_XS fallback)
                  const float*    __restrict__ wmu,
                  const float*    __restrict__ wlv,
                  const float*    __restrict__ weps,
                  const float*    __restrict__ biasp, // precomputed bias (USE_XS)
                  const float*    __restrict__ bmu,
                  const float*    __restrict__ blv,
                  const float*    __restrict__ beps,
                  float*          __restrict__ y)
{
  __shared__ __align__(16) uint8_t wsm[2][2048];     // 16 rows * 128B, swizzled

  const int tid = threadIdx.x;
  const int wv  = tid >> 6;         // wave 0..7 -> rows wv*32..wv*32+31
  const int l   = tid & 63;
  const int n0  = blockIdx.x * BN;

  // --- W staging addressing: each thread owns 2 consecutive elements of 16x64
  const int    wr   = tid >> 5;                 // row 0..15
  const int    wc   = (tid << 1) & 63;          // even col 0..62
  const size_t wgo  = (size_t)(n0 + wr) * IN_F + wc;
  const int    wlds = wr * 128 + (((wc >> 3) ^ (wr & 7)) << 4) + ((wc & 7) << 1);

  // --- fragment addressing
  const int arow  = wv * 32 + (l & 15);         // + mi*16
  const int kb    = l >> 4;                     // k-octet 0..3
  const int br    = l & 15;
  const int boff0 = br * 128 + (((kb    ) ^ (br & 7)) << 4);
  const int boff1 = br * 128 + (((kb + 4) ^ (br & 7)) << 4);

  f32x4 acc0 = {0.f, 0.f, 0.f, 0.f};
  f32x4 acc1 = {0.f, 0.f, 0.f, 0.f};

  bf16x8 aA[4], aB[4];
  f32x2  muA, lvA, epA, muB, lvB, epB;

  auto lda = [&](int t, bf16x8* d) {
    if constexpr (USE_XS) {
      const uint16_t* p = xs + (size_t)arow * IN_F + t * BK + kb * 8;
      d[0] = *(const bf16x8*)(p);
      d[1] = *(const bf16x8*)(p + 32);
      d[2] = *(const bf16x8*)(p + (size_t)16 * IN_F);
      d[3] = *(const bf16x8*)(p + (size_t)16 * IN_F + 32);
    } else {
      const float* p = xf + (size_t)arow * IN_F + t * BK + kb * 8;
      d[0] = cvt8(p);
      d[1] = cvt8(p + 32);
      d[2] = cvt8(p + (size_t)16 * IN_F);
      d[3] = cvt8(p + (size_t)16 * IN_F + 32);
    }
  };

  auto ldw = [&](int t, f32x2& mu, f32x2& lv, f32x2& ep) {
    const size_t o = wgo + (size_t)t * BK;
    mu = *(const f32x2*)(wmu + o);
    lv = *(const f32x2*)(wlv + o);
    ep = *(const f32x2*)(weps + o);
  };

  auto cvtw = [&](int buf, const f32x2& mu, const f32x2& lv, const f32x2& ep) {
    float s0 = exp2f(lv[0] * 0.7213475204444817f);
    float s1 = exp2f(lv[1] * 0.7213475204444817f);
    float w0 = fmaf(ep[0], s0, mu[0]);
    float w1 = fmaf(ep[1], s1, mu[1]);
    *(uint32_t*)(&wsm[buf][wlds]) = pack2bf(w0, w1);
  };

  auto compute = [&](int buf, const bf16x8* a) {
    bf16x8 b0 = *(const bf16x8*)(&wsm[buf][boff0]);
    bf16x8 b1 = *(const bf16x8*)(&wsm[buf][boff1]);
    acc0 = MFMA(a[0], b0, acc0);
    acc0 = MFMA(a[1], b1, acc0);
    acc1 = MFMA(a[2], b0, acc1);
    acc1 = MFMA(a[3], b1, acc1);
  };

  // ---- prologue: tile0 staged, w(1) in flight
  lda(0, aA);
  ldw(0, muA, lvA, epA);
  cvtw(0, muA, lvA, epA);          // compiler auto-waits the w(0) loads
  ldw(1, muB, lvB, epB);
  asm volatile("s_waitcnt lgkmcnt(0)" ::: "memory");
  __builtin_amdgcn_s_barrier();
  __builtin_amdgcn_sched_barrier(0);

  // ---- main loop, manually unrolled x2 to keep register banks static
  for (int t = 0; t < NT; t += 2) {
    { // iter t (even): compute buf0/aA, fill buf1 with w(t+1), prefetch t+2
      lda(t + 1, aB);
      const int tw = (t + 2 <= NT - 1) ? t + 2 : NT - 1;
      ldw(tw, muA, lvA, epA);
      cvtw(1, muB, lvB, epB);
      compute(0, aA);
      asm volatile("s_waitcnt lgkmcnt(0)" ::: "memory");
      __builtin_amdgcn_s_barrier();
      __builtin_amdgcn_sched_barrier(0);
    }
    { // iter t+1 (odd): compute buf1/aB, fill buf0 with w(t+2), prefetch t+3
      const int tn = (t + 2 <= NT - 1) ? t + 2 : NT - 1;
      lda(tn, aA);
      const int tw = (t + 3 <= NT - 1) ? t + 3 : NT - 1;
      ldw(tw, muB, lvB, epB);
      cvtw(0, muA, lvA, epA);
      compute(1, aB);
      asm volatile("s_waitcnt lgkmcnt(0)" ::: "memory");
      __builtin_amdgcn_s_barrier();
      __builtin_amdgcn_sched_barrier(0);
    }
  }

  // ---- epilogue: D[row=(l>>4)*4+i][col=l&15] per 16x16 fragment
  const int col = n0 + (l & 15);
  float bv;
  if constexpr (USE_XS) {
    bv = biasp[col];
  } else {
    bv = fmaf(beps[col], exp2f(blv[col] * 0.7213475204444817f), bmu[col]);
  }
  const int g     = l >> 4;
  const int rbase = wv * 32 + g * 4;
#pragma unroll
  for (int i = 0; i < 4; ++i)
    y[(size_t)(rbase + i) * OUT_F + col] = acc0[i] + bv;
#pragma unroll
  for (int i = 0; i < 4; ++i)
    y[(size_t)(rbase + 16 + i) * OUT_F + col] = acc1[i] + bv;
}

// ---------------------------------------------------------------------------
extern "C" void kernel_launch(void* const* d_in, const int* in_sizes, int n_in,
                              void* d_out, int out_size, void* d_ws, size_t ws_size,
                              hipStream_t stream) {
  const float* x    = (const float*)d_in[0];
  const float* wmu  = (const float*)d_in[1];
  const float* wlv  = (const float*)d_in[2];
  const float* bmu  = (const float*)d_in[3];
  const float* blv  = (const float*)d_in[4];
  const float* weps = (const float*)d_in[5];
  const float* beps = (const float*)d_in[6];
  float* y = (float*)d_out;

  const size_t xs_bytes = (size_t)BATCH * IN_F * 2;           // 2 MiB bf16 x
  const size_t need     = xs_bytes + (size_t)OUT_F * 4;       // + bias

  if (d_ws != nullptr && ws_size >= need) {
    uint16_t* xs   = (uint16_t*)d_ws;
    float*    bias = (float*)((char*)d_ws + xs_bytes);
    prep_kernel<<<528, 256, 0, stream>>>(x, bmu, blv, beps, (u32x4*)d_ws, bias);
    vgemm_kernel<true><<<OUT_F / BN, TPB, 0, stream>>>(
        xs, nullptr, wmu, wlv, weps, bias, nullptr, nullptr, nullptr, y);
  } else {
    vgemm_kernel<false><<<OUT_F / BN, TPB, 0, stream>>>(
        nullptr, x, wmu, wlv, weps, nullptr, bmu, blv, beps, y);
  }
}